// Round 13
// baseline (188.838 us; speedup 1.0000x reference)
//
#include <hip/hip_runtime.h>
#include <math.h>

#define N_NODES_C 100000
#define D_FEAT 64

// interleaved bucket geometry: bucket = node & 1023, lnode = node >> 10 (0..97)
#define NB_F 1024
#define FB_SHIFT 10
#define FB_MASK (NB_F - 1)
#define LMAX 128                       // padded local-node array (actual <= 98)
#define CAP_E 3072                     // per-bucket total cap (mean 1562 + slack)
#define COL_BITS 17                    // col < 100000 < 2^17; lnode in bits 17..23
#define COL_MASK17 0x1FFFF
#define CCS 16                         // ccursor stride (fallback path)
#define AGG_BLOCKS 512                 // fallback agg geometry (r7/r10-proven)
#define AGG_IT 8

// ---------------- fallback (round-1) atomic kernel ----------------
__global__ void spline_scatter_atomic(const float* __restrict__ x,
                                      const int* __restrict__ row_idx,
                                      const int* __restrict__ col_idx,
                                      const float* __restrict__ edge_attr,
                                      float* __restrict__ out,
                                      int n_edges) {
    long long t = (long long)blockIdx.x * blockDim.x + threadIdx.x;
    int e = (int)(t >> 6);
    int f = (int)(t & 63);
    if (e >= n_edges) return;
    int r = row_idx[e];
    int c = col_idx[e];
    float w = expf(-edge_attr[e]);
    atomicAdd(&out[(long long)r * D_FEAT + f], w * x[(long long)c * D_FEAT + f]);
}

// ---------------- legacy CSR-build pipeline (fallback #2) ----------------

__global__ void hist_kernel(const int* __restrict__ row_idx, int* __restrict__ counts,
                            int n_edges) {
    int e = blockIdx.x * blockDim.x + threadIdx.x;
    if (e < n_edges) atomicAdd(&counts[row_idx[e]], 1);
}

__global__ void scan_kernel(const int* __restrict__ counts, int* __restrict__ start,
                            int* __restrict__ cursor, int n) {
    __shared__ int wave_sums[16];
    __shared__ int carry_s;
    const int tid = threadIdx.x;
    const int lane = tid & 63;
    const int wid = tid >> 6;
    if (tid == 0) carry_s = 0;
    __syncthreads();
    for (int base = 0; base < n; base += 1024) {
        int i = base + tid;
        int v = (i < n) ? counts[i] : 0;
        int inc = v;
        #pragma unroll
        for (int d = 1; d < 64; d <<= 1) {
            int t = __shfl_up(inc, d, 64);
            if (lane >= d) inc += t;
        }
        if (lane == 63) wave_sums[wid] = inc;
        __syncthreads();
        if (tid == 0) {
            int s = carry_s;
            #pragma unroll
            for (int k = 0; k < 16; ++k) { int t = wave_sums[k]; wave_sums[k] = s; s += t; }
            carry_s = s;
        }
        __syncthreads();
        int excl = inc - v + wave_sums[wid];
        if (i < n) { start[i] = excl; cursor[i] = excl; }
        __syncthreads();
    }
    if (tid == 0) start[n] = carry_s;
}

__global__ void bucket_kernel(const int* __restrict__ row_idx,
                              const int* __restrict__ col_idx,
                              const float* __restrict__ edge_attr,
                              int* __restrict__ cursor,
                              int2* __restrict__ colw,
                              int n_edges) {
    int e = blockIdx.x * blockDim.x + threadIdx.x;
    if (e >= n_edges) return;
    int r = row_idx[e];
    int c = col_idx[e];
    float w = expf(-edge_attr[e]);
    int pos = atomicAdd(&cursor[r], 1);
    colw[pos] = make_int2(c, __float_as_int(w));
}

__global__ void gather_accum_kernel(const float* __restrict__ x,
                                    const int* __restrict__ start,
                                    const int2* __restrict__ colw,
                                    float* __restrict__ out,
                                    int n_nodes) {
    int node = blockIdx.x * (blockDim.x >> 6) + (threadIdx.x >> 6);
    int lane = threadIdx.x & 63;
    if (node >= n_nodes) return;
    int b = start[node];
    int e = start[node + 1];
    float acc = 0.0f;
    int j = b;
    for (; j + 3 < e; j += 4) {
        int2 c0 = colw[j], c1 = colw[j + 1], c2 = colw[j + 2], c3 = colw[j + 3];
        acc += __int_as_float(c0.y) * x[(size_t)c0.x * D_FEAT + lane];
        acc += __int_as_float(c1.y) * x[(size_t)c1.x * D_FEAT + lane];
        acc += __int_as_float(c2.y) * x[(size_t)c2.x * D_FEAT + lane];
        acc += __int_as_float(c3.y) * x[(size_t)c3.x * D_FEAT + lane];
    }
    for (; j < e; ++j) {
        int2 c0 = colw[j];
        acc += __int_as_float(c0.y) * x[(size_t)c0.x * D_FEAT + lane];
    }
    out[(size_t)node * D_FEAT + lane] = acc;
}

// ---------------- fallback #1: proven 3-dispatch fast path (r7/r10) ----------------

__global__ __launch_bounds__(512) void agg_scatter3_kernel(const int* __restrict__ row,
                                                           const int* __restrict__ col,
                                                           const float* __restrict__ attr,
                                                           int* __restrict__ ccursor,
                                                           int2* __restrict__ cw,
                                                           int n_edges, int chunk) {
    __shared__ int h[NB_F];
    __shared__ int gbase[NB_F];
    __shared__ int lcur[NB_F];
    const int tid = threadIdx.x;
    const int base = blockIdx.x * chunk;
    const int end = min(base + chunk, n_edges);
    #pragma unroll
    for (int i = tid; i < NB_F; i += 512) { h[i] = 0; lcur[i] = 0; }
    __syncthreads();
    int rc[AGG_IT];
    #pragma unroll
    for (int k = 0; k < AGG_IT; ++k) {
        int e = base + k * 512 + tid;
        rc[k] = (e < end) ? row[e] : -1;
        if (rc[k] >= 0) atomicAdd(&h[rc[k] & FB_MASK], 1);
    }
    __syncthreads();
    #pragma unroll
    for (int i = tid; i < NB_F; i += 512) {
        int c = h[i];
        gbase[i] = c ? atomicAdd(&ccursor[i * CCS], c) : 0;
    }
    __syncthreads();
    #pragma unroll
    for (int k = 0; k < AGG_IT; ++k) {
        int e = base + k * 512 + tid;
        int r = rc[k];
        if (r >= 0) {
            int b = r & FB_MASK;
            float w = expf(-attr[e]);
            int rel = gbase[b] + atomicAdd(&lcur[b], 1);
            if (rel < CAP_E)
                cw[(size_t)b * CAP_E + rel] =
                    make_int2(col[e] | ((r >> FB_SHIFT) << COL_BITS), __float_as_int(w));
        }
    }
}

__global__ __launch_bounds__(512, 8) void bucket_fused5_kernel(const float* __restrict__ x,
                                                               const int2* __restrict__ cw,
                                                               const int* __restrict__ ccursor,
                                                               float* __restrict__ out,
                                                               int n_nodes) {
    __shared__ int2 sorted[CAP_E];
    __shared__ int lhist[LMAX];
    __shared__ int lbase[LMAX];
    __shared__ int lcur[LMAX];
    __shared__ int wsum[2];
    const int b = blockIdx.x;
    const int tid = threadIdx.x;
    const int lane = tid & 63;
    const int wid = tid >> 6;
    const size_t beg = (size_t)b * CAP_E;
    int n = ccursor[b * CCS];
    if (n > CAP_E) n = CAP_E;
    if (tid < LMAX) lhist[tid] = 0;
    __syncthreads();
    int2 my[CAP_E / 512];
    #pragma unroll
    for (int k = 0; k < CAP_E / 512; ++k) {
        int i = tid + k * 512;
        if (i < n) {
            int2 d = cw[beg + i];
            my[k] = d;
            atomicAdd(&lhist[d.x >> COL_BITS], 1);
        }
    }
    __syncthreads();
    int v = 0, inc = 0;
    if (tid < LMAX) {
        v = lhist[tid];
        inc = v;
        #pragma unroll
        for (int d = 1; d < 64; d <<= 1) {
            int t = __shfl_up(inc, d, 64);
            if (lane >= d) inc += t;
        }
        if (lane == 63) wsum[wid] = inc;
    }
    __syncthreads();
    if (tid == 0) { int s = 0; for (int k = 0; k < 2; ++k) { int t = wsum[k]; wsum[k] = s; s += t; } }
    __syncthreads();
    if (tid < LMAX) { int excl = inc - v + wsum[wid]; lbase[tid] = excl; lcur[tid] = excl; }
    __syncthreads();
    #pragma unroll
    for (int k = 0; k < CAP_E / 512; ++k) {
        int i = tid + k * 512;
        if (i < n) {
            int2 d = my[k];
            int p = atomicAdd(&lcur[d.x >> COL_BITS], 1);
            sorted[p] = make_int2(d.x & COL_MASK17, d.y);
        }
    }
    __syncthreads();
    const int sl = tid & 15;
    const int grp = tid >> 4;
    const float* xb = x + (sl << 2);
    #pragma unroll
    for (int t2 = 0; t2 < 4; ++t2) {
        int ln = t2 * 32 + grp;
        int node = b + (ln << FB_SHIFT);
        int s = lbase[ln];
        int e2 = (ln + 1 < LMAX) ? lbase[ln + 1] : n;
        float4 acc = make_float4(0.f, 0.f, 0.f, 0.f);
        int j = s;
        for (; j + 8 <= e2; j += 8) {
            #pragma unroll
            for (int k = 0; k < 8; ++k) {
                int2 d = sorted[j + k];
                const float4 xv = *(const float4*)(xb + ((size_t)d.x << 6));
                float w = __int_as_float(d.y);
                acc.x += w * xv.x; acc.y += w * xv.y; acc.z += w * xv.z; acc.w += w * xv.w;
            }
        }
        #pragma unroll
        for (int k = 0; k < 7; ++k) {
            if (j + k < e2) {
                int2 d = sorted[j + k];
                const float4 xv = *(const float4*)(xb + ((size_t)d.x << 6));
                float w = __int_as_float(d.y);
                acc.x += w * xv.x; acc.y += w * xv.y; acc.z += w * xv.z; acc.w += w * xv.w;
            }
        }
        if (node < n_nodes)
            *(float4*)(out + ((size_t)node << 6) + (sl << 2)) = acc;
    }
}

// ---------------- primary: single producer/consumer kernel ----------------
// Normal launch + device-scope atomics/fences (the r11 coop-launch path made
// all memory uncached-slow; this is the guide-sanctioned alternative).
// Producers = blocks 0..nprod-1 (dispatched first -> no residency deadlock):
// single pass, append into exclusively-owned (bucket,producer) cells of cw2
// (line-aligned, single-writer -> no cross-XCD partial-line write amp, no
// global atomics, no hist pass). Release: threadfence + agent-scope add(done).
// Consumers = all blocks: acquire-spin on done, then per-bucket cell-prefix,
// LDS lnode-sort (two passes over cells), then the r9-proven gather verbatim.
__global__ __launch_bounds__(512, 8) void mega_pipe_kernel(const float* __restrict__ x,
                                                           const int* __restrict__ row,
                                                           const int* __restrict__ col,
                                                           const float* __restrict__ attr,
                                                           int2* __restrict__ cw2,
                                                           int* __restrict__ cntT,
                                                           int* __restrict__ done,
                                                           float* __restrict__ out,
                                                           int n_edges, int n_nodes,
                                                           int nprod, int subcap, int chunk) {
    __shared__ int lcurP[NB_F];          // 4 KB  (producer append cursors)
    __shared__ int2 sorted[CAP_E];       // 24 KB
    __shared__ int lhist[LMAX];
    __shared__ int lbase[LMAX];
    __shared__ int lcur[LMAX];
    __shared__ int pcnt[64];
    __shared__ int ppre[64];
    __shared__ int wsum[2];
    __shared__ int ptot;
    const int tid = threadIdx.x;
    const int bid = blockIdx.x;
    const int lane = tid & 63;
    const int wid = tid >> 6;

    // ---- produce ----
    if (bid < nprod) {
        for (int i = tid; i < NB_F; i += 512) lcurP[i] = 0;
        __syncthreads();
        const int base = bid * chunk;
        const int end = min(base + chunk, n_edges);
        for (int e = base + tid; e < end; e += 512) {
            int r = row[e];
            int b = r & FB_MASK;
            int pos = atomicAdd(&lcurP[b], 1);          // native LDS int atomic
            if (pos < subcap) {
                float w = expf(-attr[e]);
                cw2[((size_t)b * nprod + bid) * subcap + pos] =
                    make_int2(col[e] | ((r >> FB_SHIFT) << COL_BITS), __float_as_int(w));
            }
        }
        __syncthreads();
        for (int i = tid; i < NB_F; i += 512)
            cntT[(size_t)bid * NB_F + i] = min(lcurP[i], subcap);   // contiguous 4KB
        __syncthreads();   // drains all block stores (vmcnt0 before barrier)
        if (tid == 0) {
            __threadfence();                                        // wbL2: device-visible
            __hip_atomic_fetch_add(done, 1, __ATOMIC_RELEASE, __HIP_MEMORY_SCOPE_AGENT);
        }
    }

    // ---- wait for all producers (agent-scope acquire; s_sleep backoff) ----
    if (tid == 0) {
        long long guard = 0;
        while (__hip_atomic_load(done, __ATOMIC_ACQUIRE, __HIP_MEMORY_SCOPE_AGENT) < nprod) {
            __builtin_amdgcn_s_sleep(32);
            if (++guard > 2000000LL) break;   // ~1.7s safety valve; never triggers
        }
        __threadfence();                      // inv stale lines before cw2 reads
    }
    __syncthreads();

    // ---- consume bucket bid ----
    const int b = bid;
    if (tid < 64) { pcnt[tid] = 0; ppre[tid] = 0; }
    if (tid < LMAX) lhist[tid] = 0;
    __syncthreads();
    if (tid < nprod) {            // nprod <= 64: all in wave 0
        int c = cntT[(size_t)tid * NB_F + b];
        if (c > subcap) c = subcap;
        pcnt[tid] = c;
        int inc = c;
        #pragma unroll
        for (int d = 1; d < 64; d <<= 1) {
            int t = __shfl_up(inc, d, 64);
            if (lane >= d) inc += t;
        }
        ppre[tid] = inc - c;
        if (tid == nprod - 1) ptot = inc;
    }
    __syncthreads();
    int n = ptot;
    if (n > CAP_E) n = CAP_E;

    // pass A: lnode histogram over this bucket's cells
    for (int k = wid; k < nprod; k += 8) {
        int base2 = ppre[k];
        int c = pcnt[k];
        const int2* cell = cw2 + ((size_t)b * nprod + k) * subcap;
        for (int i = lane; i < c; i += 64) {
            if (base2 + i < CAP_E) {
                int2 d = cell[i];
                atomicAdd(&lhist[d.x >> COL_BITS], 1);
            }
        }
    }
    __syncthreads();
    // scan lhist[0..127]
    int v = 0, inc2 = 0;
    if (tid < LMAX) {
        v = lhist[tid];
        inc2 = v;
        #pragma unroll
        for (int d = 1; d < 64; d <<= 1) {
            int t = __shfl_up(inc2, d, 64);
            if (lane >= d) inc2 += t;
        }
        if (lane == 63) wsum[wid] = inc2;
    }
    __syncthreads();
    if (tid == 0) { int s = 0; for (int k = 0; k < 2; ++k) { int t = wsum[k]; wsum[k] = s; s += t; } }
    __syncthreads();
    if (tid < LMAX) { int excl = inc2 - v + wsum[wid]; lbase[tid] = excl; lcur[tid] = excl; }
    __syncthreads();
    // pass B: place into lnode-sorted LDS order (cells L2-hot from pass A)
    for (int k = wid; k < nprod; k += 8) {
        int base2 = ppre[k];
        int c = pcnt[k];
        const int2* cell = cw2 + ((size_t)b * nprod + k) * subcap;
        for (int i = lane; i < c; i += 64) {
            if (base2 + i < CAP_E) {
                int2 d = cell[i];
                int p = atomicAdd(&lcur[d.x >> COL_BITS], 1);
                sorted[p] = make_int2(d.x & COL_MASK17, d.y);
            }
        }
    }
    __syncthreads();

    // gather (r9-proven, unchanged)
    const int sl = tid & 15;
    const int grp = tid >> 4;
    const float* xb = x + (sl << 2);
    #pragma unroll
    for (int t2 = 0; t2 < 4; ++t2) {
        int ln = t2 * 32 + grp;
        int node = b + (ln << FB_SHIFT);
        int s = lbase[ln];
        int e2 = (ln + 1 < LMAX) ? lbase[ln + 1] : n;
        float4 acc = make_float4(0.f, 0.f, 0.f, 0.f);
        int j = s;
        for (; j + 8 <= e2; j += 8) {
            #pragma unroll
            for (int k = 0; k < 8; ++k) {
                int2 d = sorted[j + k];
                const float4 xv = *(const float4*)(xb + ((size_t)d.x << 6));
                float w = __int_as_float(d.y);
                acc.x += w * xv.x; acc.y += w * xv.y; acc.z += w * xv.z; acc.w += w * xv.w;
            }
        }
        #pragma unroll
        for (int k = 0; k < 7; ++k) {
            if (j + k < e2) {
                int2 d = sorted[j + k];
                const float4 xv = *(const float4*)(xb + ((size_t)d.x << 6));
                float w = __int_as_float(d.y);
                acc.x += w * xv.x; acc.y += w * xv.y; acc.z += w * xv.z; acc.w += w * xv.w;
            }
        }
        if (node < n_nodes)
            *(float4*)(out + ((size_t)node << 6) + (sl << 2)) = acc;
    }
}

extern "C" void kernel_launch(void* const* d_in, const int* in_sizes, int n_in,
                              void* d_out, int out_size, void* d_ws, size_t ws_size,
                              hipStream_t stream) {
    const float* x    = (const float*)d_in[0];
    const int*   eidx = (const int*)d_in[1];   // flat (2, E): [row | col]
    const float* attr = (const float*)d_in[2];
    float*       out  = (float*)d_out;

    const int n_edges = in_sizes[2];
    const int n_nodes = N_NODES_C;
    const int* row = eidx;
    const int* col = eidx + n_edges;

    // ---------- primary: single-kernel producer/consumer ----------
    // pick largest nprod whose layout fits ws:
    //   cw2[NB_F][nprod][subcap] int2 + cntT[nprod][NB_F] int + done (64B)
    // stats: cell ~ Binomial(chunk, 1/NB_F); subcap >= mean + ~6.5 sigma
    const int cfg_nprod[2]  = {64, 32};
    const int cfg_subcap[2] = {56, 96};    // 24.4+6.4s=56 | 48.8+6.8s=96
    for (int c = 0; c < 2; ++c) {
        const int nprod = cfg_nprod[c], subcap = cfg_subcap[c];
        size_t off_cw2  = 0;
        size_t off_cnt  = off_cw2 + (size_t)NB_F * nprod * subcap * sizeof(int2);
        size_t off_done = (off_cnt + (size_t)nprod * NB_F * sizeof(int) + 63) & ~(size_t)63;
        size_t need     = off_done + 64;
        if (ws_size < need) continue;
        const int chunk = (n_edges + nprod - 1) / nprod;
        const double mean = (double)chunk / (double)NB_F;
        if (mean + 6.5 * sqrt(mean) + 2.0 > (double)subcap) continue;
        if (n_nodes > NB_F * LMAX) break;

        char* ws = (char*)d_ws;
        int2* cw2  = (int2*)(ws + off_cw2);
        int*  cntT = (int*)(ws + off_cnt);
        int*  done = (int*)(ws + off_done);

        hipMemsetAsync(done, 0, 8, stream);
        mega_pipe_kernel<<<NB_F, 512, 0, stream>>>(x, row, col, attr, cw2, cntT, done,
                                                   out, n_edges, n_nodes, nprod, subcap,
                                                   chunk);
        return;
    }

    // ---------- fallback #1: proven 3-dispatch fast path ----------
    {
        size_t off_cw   = 0;
        size_t off_ccur = off_cw + (size_t)NB_F * CAP_E * sizeof(int2);
        size_t need     = off_ccur + (size_t)NB_F * CCS * sizeof(int);
        const int chunk = (n_edges + AGG_BLOCKS - 1) / AGG_BLOCKS;
        const double mean_fill = (double)n_edges / (double)NB_F;
        bool ok = (mean_fill + 12.0 * sqrt(mean_fill) + 128.0) <= (double)CAP_E;
        ok = ok && (chunk <= 512 * AGG_IT) && (n_nodes <= NB_F * LMAX);
        if (ws_size >= need && ok) {
            char* ws = (char*)d_ws;
            int2* cw      = (int2*)(ws + off_cw);
            int*  ccursor = (int*)(ws + off_ccur);
            hipMemsetAsync(ccursor, 0, (size_t)NB_F * CCS * sizeof(int), stream);
            agg_scatter3_kernel<<<AGG_BLOCKS, 512, 0, stream>>>(row, col, attr, ccursor,
                                                                cw, n_edges, chunk);
            bucket_fused5_kernel<<<NB_F, 512, 0, stream>>>(x, cw, ccursor, out, n_nodes);
            return;
        }
    }

    // ---------- legacy CSR layout (fallback #2) ----------
    size_t l_off_colw   = 0;
    size_t l_off_counts = l_off_colw + (size_t)n_edges * sizeof(int2);
    size_t l_off_start  = l_off_counts + (size_t)n_nodes * sizeof(int);
    size_t l_off_cursor = l_off_start + (size_t)(n_nodes + 1) * sizeof(int);
    size_t ws_needed_old = l_off_cursor + (size_t)n_nodes * sizeof(int);

    if (ws_size >= ws_needed_old) {
        char* ws = (char*)d_ws;
        int2* colw   = (int2*)(ws + l_off_colw);
        int*  counts = (int*)(ws + l_off_counts);
        int*  start  = (int*)(ws + l_off_start);
        int*  cursor = (int*)(ws + l_off_cursor);

        hipMemsetAsync(counts, 0, (size_t)n_nodes * sizeof(int), stream);

        const int eb = (n_edges + 255) / 256;
        hist_kernel<<<eb, 256, 0, stream>>>(row, counts, n_edges);
        scan_kernel<<<1, 1024, 0, stream>>>(counts, start, cursor, n_nodes);
        bucket_kernel<<<eb, 256, 0, stream>>>(row, col, attr, cursor, colw, n_edges);

        const int waves_per_block = 4;
        const int nb = (n_nodes + waves_per_block - 1) / waves_per_block;
        gather_accum_kernel<<<nb, 256, 0, stream>>>(x, start, colw, out, n_nodes);
        return;
    }

    // ---------- last resort: atomic kernel ----------
    hipMemsetAsync(out, 0, (size_t)out_size * sizeof(float), stream);
    const long long total = (long long)n_edges * 64;
    const int blocks = (int)((total + 255) / 256);
    spline_scatter_atomic<<<blocks, 256, 0, stream>>>(x, row, col, attr, out, n_edges);
}